// Round 4
// baseline (453.471 us; speedup 1.0000x reference)
//
#include <hip/hip_runtime.h>

typedef _Float16 f16;
typedef f16 f16x8 __attribute__((ext_vector_type(8)));
typedef f16 f16x4 __attribute__((ext_vector_type(4)));
typedef __fp16 h16x2 __attribute__((ext_vector_type(2)));   // cvt_pkrtz native type
typedef float f32x4 __attribute__((ext_vector_type(4)));
typedef float f32x2 __attribute__((ext_vector_type(2)));

#define MFMA16(A, B, C) __builtin_amdgcn_mfma_f32_16x16x32_f16((A), (B), (C), 0, 0, 0)

// Barrier WITHOUT vmcnt drain: only LDS (lgkmcnt) must be visible across it.
// (R6: LDS flag sync is WORSE than s_barrier; __syncthreads would drain vmcnt
// and serialize the in-flight x prefetch.)
#define LDS_BARRIER() asm volatile("s_waitcnt lgkmcnt(0)\n\ts_barrier" ::: "memory")

__device__ __forceinline__ float E2(float x) {   // 2^x
#if __has_builtin(__builtin_amdgcn_exp2f)
  return __builtin_amdgcn_exp2f(x);
#else
  return __expf(x * 0.69314718056f);
#endif
}

__device__ __forceinline__ f16x8 cvt8(float4 a, float4 b) {
  union { h16x2 h[4]; f16x8 v; } u;
  u.h[0] = __builtin_amdgcn_cvt_pkrtz(a.x, a.y);
  u.h[1] = __builtin_amdgcn_cvt_pkrtz(a.z, a.w);
  u.h[2] = __builtin_amdgcn_cvt_pkrtz(b.x, b.y);
  u.h[3] = __builtin_amdgcn_cvt_pkrtz(b.z, b.w);
  return u.v;
}

// scaled weight-load convert (init-time only)
__device__ __forceinline__ f16x8 cvt8s(const float* p, float s) {
  float4 a = *(const float4*)p;
  float4 b = *(const float4*)(p + 4);
  union { h16x2 h[4]; f16x8 v; } u;
  u.h[0] = __builtin_amdgcn_cvt_pkrtz(a.x * s, a.y * s);
  u.h[1] = __builtin_amdgcn_cvt_pkrtz(a.z * s, a.w * s);
  u.h[2] = __builtin_amdgcn_cvt_pkrtz(b.x * s, b.y * s);
  u.h[3] = __builtin_amdgcn_cvt_pkrtz(b.z * s, b.w * s);
  return u.v;
}

__device__ __forceinline__ f16x4 pack4(f32x2 a, f32x2 b) {
  union { h16x2 h2[2]; f16x4 v; } u;
  u.h2[0] = __builtin_amdgcn_cvt_pkrtz(a[0], a[1]);
  u.h2[1] = __builtin_amdgcn_cvt_pkrtz(b[0], b[1]);
  return u.v;
}

// Packed gate math for a pair of h-rows.  float2 ops -> v_pk_*_f32.
// Gate pre-scales are FOLDED INTO THE WEIGHTS/BIASES at load time:
//   aR,aZ arrive pre-multiplied by -log2(e)    -> ea = 2^aR = e^{-pre}
//   aXN,aHN arrive pre-multiplied by -2log2(e) -> my = aXN + r*aHN = -2log2e*y
// sigmoid pair shares one rcp; tanh(y) = (1-c)*rcp(1+c), c = 2^(-2log2e*y).
// Verified R7: absmax 0.0039 (unchanged).
__device__ __forceinline__ void gates_pair(f32x2 aR, f32x2 aZ, f32x2 aXN,
                                           f32x2 aHN, f32x2& hs) {
  f32x2 ea, eb;
  ea[0] = E2(aR[0]); ea[1] = E2(aR[1]);
  eb[0] = E2(aZ[0]); eb[1] = E2(aZ[1]);
  f32x2 pa = ea + 1.0f;
  f32x2 pb = eb + 1.0f;
  f32x2 prod = pa * pb;
  f32x2 inv;
  inv[0] = __builtin_amdgcn_rcpf(prod[0]);
  inv[1] = __builtin_amdgcn_rcpf(prod[1]);
  f32x2 rg = pb * inv;                 // sigmoid(r pre-act)
  f32x2 zg = pa * inv;                 // sigmoid(z pre-act)
  f32x2 my = aXN + rg * aHN;           // = -2log2e * (xn + r*hn)
  f32x2 c;
  c[0] = E2(my[0]); c[1] = E2(my[1]);
  f32x2 num = 1.0f - c;
  f32x2 den = 1.0f + c;
  f32x2 rin;
  rin[0] = __builtin_amdgcn_rcpf(den[0]);
  rin[1] = __builtin_amdgcn_rcpf(den[1]);
  f32x2 ng = num * rin;                // tanh(y)
  hs = zg * (hs - ng) + ng;
}

// B=4096, T=128, D=32, H=64.  R10: 16 batch / WG, 256 WGs, **1024 threads,
// 16 waves** — 4 waves/SIMD inside ONE workgroup.
//
// Why: R2/R3 showed a second 512-thread WG won't co-schedule on a CU above
// ~64 VGPR (R3: 80 VGPR, occupancy stuck at 22%, WGs serialized; R2: 64
// VGPR co-resided but only by spilling the weights).  A single WG's waves
// ALWAYS co-reside, so we get 4 waves/SIMD by splitting each role-wave's
// 16 gate-rows across two waves of 8 REAL rows (A-frag rows duplicated via
// l15&7; MFMA C-rows 8-15 are exact duplicates of 0-7; lanes q>=2 carry
// inert mirrored state and never write).  Per-wave instruction count is
// row-count-independent -> per-SIMD issue doubles, filling stall cycles.
//
// Waves 0-7 (group A): layer 0, step t; wave sub=w&7 owns gate-rows
// [8*sub, 8*sub+8).  Waves 8-15 (group B): layer 1, step t-1, same split.
// Time loop unrolled x2 (parity/prefetch compile-time; R4: runtime-indexed
// arrays -> scratch).  One LDS-only s_barrier per pipeline step.
// H LDS layout: h[k] for batch b at f16 offset ((k>>3)*16+b)*8 + (k&7)
//   -> B-frag for lane L, kfrag f = stride-1 ds_read_b128 at f*1024 + L*16.
__launch_bounds__(1024, 1)
__global__ void gru_fused(const float* __restrict__ x,
                          const float* __restrict__ Wih0, const float* __restrict__ Whh0,
                          const float* __restrict__ bih0, const float* __restrict__ bhh0,
                          const float* __restrict__ Wih1, const float* __restrict__ Whh1,
                          const float* __restrict__ bih1, const float* __restrict__ bhh1,
                          const float* __restrict__ fcw, const float* __restrict__ fcb,
                          float* __restrict__ out) {
  __shared__ f16 H0[2][1024];
  __shared__ f16 H1[2][1024];
  __shared__ float red[8][16];

  const int tid = threadIdx.x;
  const int wave = tid >> 6;          // 0..15
  const int lane = tid & 63;
  const int l15 = lane & 15;
  const int q = lane >> 4;            // 0..3; q>=2 = duplicate half
  const int sub = wave & 7;           // row-block [8*sub, 8*sub+8)
  const bool isB = wave >= 8;
  const int b0 = blockIdx.x * 16;

  for (int i = tid; i < 2048; i += 1024) {
    ((f16*)H0)[i] = (f16)0.0f;
    ((f16*)H1)[i] = (f16)0.0f;
  }

  const float SRZ = -1.44269504f;     // -log2(e)      folded into r,z rows
  const float SN  = -2.88539008f;     // -2*log2(e)    folded into n rows

  // ---- register-resident weight A-fragments: A[m=l15][k = kf*32 + q*8 + j]
  // Real rows are 8*sub + (l15&7); l15>=8 duplicates -> C rows 8-15 dup 0-7.
  f16x8 wAx[3];          // layer0 Wih (K=32)       — group A only
  f16x8 wAh[3][2];       // layer0 Whh (K=64)       — group A only
  f16x8 wBx[3][2];       // layer1 Wih (K=64)       — group B only
  f16x8 wBh[3][2];       // layer1 Whh (K=64)       — group B only
  f32x4 bR, bZ, bXN, bHN;
  float fw[4] = {0.f, 0.f, 0.f, 0.f};

  // Mirrored bias row for q>=2 keeps duplicate lanes bit-identical to q-2.
  const int ob = 8 * sub + 4 * (q & 1);

  if (!isB) {
#pragma unroll
    for (int g = 0; g < 3; ++g) {
      const float s = (g == 2) ? SN : SRZ;
      const int row = g * 64 + 8 * sub + (l15 & 7);
      wAx[g] = cvt8s(Wih0 + row * 32 + q * 8, s);
#pragma unroll
      for (int kf = 0; kf < 2; ++kf) {
        wAh[g][kf] = cvt8s(Whh0 + row * 64 + kf * 32 + q * 8, s);
      }
    }
#pragma unroll
    for (int r = 0; r < 4; ++r) {
      const int o = ob + r;
      bR[r]  = SRZ * (bih0[o] + bhh0[o]);
      bZ[r]  = SRZ * (bih0[64 + o] + bhh0[64 + o]);
      bXN[r] = SN * bih0[128 + o];
      bHN[r] = SN * bhh0[128 + o];
    }
  } else {
#pragma unroll
    for (int g = 0; g < 3; ++g) {
      const float s = (g == 2) ? SN : SRZ;
      const int row = g * 64 + 8 * sub + (l15 & 7);
#pragma unroll
      for (int kf = 0; kf < 2; ++kf) {
        wBx[g][kf] = cvt8s(Wih1 + row * 64 + kf * 32 + q * 8, s);
        wBh[g][kf] = cvt8s(Whh1 + row * 64 + kf * 32 + q * 8, s);
      }
    }
#pragma unroll
    for (int r = 0; r < 4; ++r) {
      const int o = ob + r;
      bR[r]  = SRZ * (bih1[o] + bhh1[o]);
      bZ[r]  = SRZ * (bih1[64 + o] + bhh1[64 + o]);
      bXN[r] = SN * bih1[128 + o];
      bHN[r] = SN * bhh1[128 + o];
      fw[r] = (q < 2) ? fcw[o] : 0.f;   // duplicate lanes contribute 0 to fc
    }
  }
  const float fcb0 = fcb[0];

  f32x2 hs01 = {0.f, 0.f}, hs23 = {0.f, 0.f};  // this lane's 4 h rows (own layer)

  const bool wr = (q < 2);                                  // real-row lanes
  const int wk0 = ob;                                       // lane's h-row base
  const int widx = ((wk0 >> 3) * 16 + l15) * 8 + (wk0 & 7); // f16 offset of its b64 store

  // layer-0 step: read H0r, consume x frag, write H0w (q<2 lanes only)
  auto stepA = [&](const f16* H0r, f16* H0w, float4 xav, float4 xbv) {
    const f16x8 xf = cvt8(xav, xbv);
    const f16x8 h0f0 = *(const f16x8*)&H0r[lane * 8];
    const f16x8 h0f1 = *(const f16x8*)&H0r[512 + lane * 8];
    f32x4 aR  = MFMA16(wAx[0], xf, bR);
    f32x4 aZ  = MFMA16(wAx[1], xf, bZ);
    f32x4 aXN = MFMA16(wAx[2], xf, bXN);
    f32x4 aHN = MFMA16(wAh[2][0], h0f0, bHN);
    aR  = MFMA16(wAh[0][0], h0f0, aR);
    aZ  = MFMA16(wAh[1][0], h0f0, aZ);
    aR  = MFMA16(wAh[0][1], h0f1, aR);
    aZ  = MFMA16(wAh[1][1], h0f1, aZ);
    aHN = MFMA16(wAh[2][1], h0f1, aHN);
    gates_pair(f32x2{aR[0], aR[1]}, f32x2{aZ[0], aZ[1]},
               f32x2{aXN[0], aXN[1]}, f32x2{aHN[0], aHN[1]}, hs01);
    gates_pair(f32x2{aR[2], aR[3]}, f32x2{aZ[2], aZ[3]},
               f32x2{aXN[2], aXN[3]}, f32x2{aHN[2], aHN[3]}, hs23);
    if (wr) *(f16x4*)&H0w[widx] = pack4(hs01, hs23);
  };

  // layer-1 step: read h0 from H0r, own state from H1r, write H1w (q<2 only)
  auto stepB = [&](const f16* H0r, const f16* H1r, f16* H1w) {
    const f16x8 g0 = *(const f16x8*)&H0r[lane * 8];
    const f16x8 g1 = *(const f16x8*)&H0r[512 + lane * 8];
    const f16x8 h1f0 = *(const f16x8*)&H1r[lane * 8];
    const f16x8 h1f1 = *(const f16x8*)&H1r[512 + lane * 8];
    f32x4 aR  = MFMA16(wBx[0][0], g0, bR);
    f32x4 aZ  = MFMA16(wBx[1][0], g0, bZ);
    f32x4 aXN = MFMA16(wBx[2][0], g0, bXN);
    aR  = MFMA16(wBx[0][1], g1, aR);
    aZ  = MFMA16(wBx[1][1], g1, aZ);
    aXN = MFMA16(wBx[2][1], g1, aXN);
    f32x4 aHN = MFMA16(wBh[2][0], h1f0, bHN);
    aR  = MFMA16(wBh[0][0], h1f0, aR);
    aZ  = MFMA16(wBh[1][0], h1f0, aZ);
    aR  = MFMA16(wBh[0][1], h1f1, aR);
    aZ  = MFMA16(wBh[1][1], h1f1, aZ);
    aHN = MFMA16(wBh[2][1], h1f1, aHN);
    gates_pair(f32x2{aR[0], aR[1]}, f32x2{aZ[0], aZ[1]},
               f32x2{aXN[0], aXN[1]}, f32x2{aHN[0], aHN[1]}, hs01);
    gates_pair(f32x2{aR[2], aR[3]}, f32x2{aZ[2], aZ[3]},
               f32x2{aXN[2], aXN[3]}, f32x2{aHN[2], aHN[3]}, hs23);
    if (wr) *(f16x4*)&H1w[widx] = pack4(hs01, hs23);
  };

  __syncthreads();

  // x B-frag source (group A waves): lane (l15,q) reads x[b0+l15][t][q*8..].
  // All 8 A-waves load the same lines; L1 absorbs the redundancy.
  const float* xbase = x + (size_t)(b0 + l15) * 4096 + q * 8;
  float4 xa0, xb0, xa1, xb1;
  if (!isB) {
    xa0 = *(const float4*)xbase;
    xb0 = *(const float4*)(xbase + 4);
    xa1 = *(const float4*)(xbase + 32);
    xb1 = *(const float4*)(xbase + 36);
  }

  for (int t = 0; t < 128; t += 2) {
    // ---- pipeline iteration t (parity 0): A step t, B step t-1
    if (!isB) {
      const float4 cxa = xa0, cxb = xb0;
      if (t + 2 < 128) {
        const float* xp = xbase + (t + 2) * 32;
        xa0 = *(const float4*)xp;
        xb0 = *(const float4*)(xp + 4);
      }
      stepA(H0[0], H0[1], cxa, cxb);
    } else if (t > 0) {
      stepB(H0[0], H1[0], H1[1]);
    }
    LDS_BARRIER();

    // ---- pipeline iteration t+1 (parity 1): A step t+1, B step t
    if (!isB) {
      const float4 cxa = xa1, cxb = xb1;
      if (t + 3 < 128) {
        const float* xp = xbase + (t + 3) * 32;
        xa1 = *(const float4*)xp;
        xb1 = *(const float4*)(xp + 4);
      }
      stepA(H0[1], H0[0], cxa, cxb);
    } else {
      stepB(H0[1], H1[1], H1[0]);
    }
    LDS_BARRIER();
  }
  // ---- pipeline iteration t=128 (parity 0): B step 127 only
  if (isB) stepB(H0[0], H1[0], H1[1]);

  // ---- fc: out[b] = sum_i h1[i]*fcw[i] + fcb   (group B holds h1(127);
  //      q>=2 duplicate lanes have fw=0 so they contribute nothing)
  if (isB) {
    float partial = fw[0] * hs01[0] + fw[1] * hs01[1] + fw[2] * hs23[0] + fw[3] * hs23[1];
    partial += __shfl_down(partial, 16, 64);
    partial += __shfl_down(partial, 32, 64);
    if (lane < 16) red[sub][l15] = partial;
  }
  __syncthreads();
  if (tid < 16) {
    float s = red[0][tid] + red[1][tid] + red[2][tid] + red[3][tid] +
              red[4][tid] + red[5][tid] + red[6][tid] + red[7][tid];
    out[b0 + tid] = s + fcb0;
  }
}

extern "C" void kernel_launch(void* const* d_in, const int* in_sizes, int n_in,
                              void* d_out, int out_size, void* d_ws, size_t ws_size,
                              hipStream_t stream) {
  (void)in_sizes; (void)n_in; (void)out_size; (void)d_ws; (void)ws_size;
  const float* x    = (const float*)d_in[0];
  const float* Wih0 = (const float*)d_in[1];
  const float* Whh0 = (const float*)d_in[2];
  const float* bih0 = (const float*)d_in[3];
  const float* bhh0 = (const float*)d_in[4];
  const float* Wih1 = (const float*)d_in[5];
  const float* Whh1 = (const float*)d_in[6];
  const float* bih1 = (const float*)d_in[7];
  const float* bhh1 = (const float*)d_in[8];
  const float* fcw  = (const float*)d_in[9];
  const float* fcb  = (const float*)d_in[10];
  float* out = (float*)d_out;

  gru_fused<<<256, 1024, 0, stream>>>(x, Wih0, Whh0, bih0, bhh0,
                                      Wih1, Whh1, bih1, bhh1, fcw, fcb, out);
}

// Round 5
// 451.443 us; speedup vs baseline: 1.0045x; 1.0045x over previous
//
#include <hip/hip_runtime.h>

typedef _Float16 f16;
typedef f16 f16x8 __attribute__((ext_vector_type(8)));
typedef f16 f16x4 __attribute__((ext_vector_type(4)));
typedef __fp16 h16x2 __attribute__((ext_vector_type(2)));   // cvt_pkrtz native type
typedef float f32x4 __attribute__((ext_vector_type(4)));
typedef float f32x2 __attribute__((ext_vector_type(2)));

#define MFMA16(A, B, C) __builtin_amdgcn_mfma_f32_16x16x32_f16((A), (B), (C), 0, 0, 0)

// Barrier WITHOUT vmcnt drain: only LDS (lgkmcnt) must be visible across it.
// (R6: LDS flag sync is WORSE than s_barrier; __syncthreads would drain vmcnt
// and serialize the in-flight x prefetch.)
#define LDS_BARRIER() asm volatile("s_waitcnt lgkmcnt(0)\n\ts_barrier" ::: "memory")

__device__ __forceinline__ float E2(float x) {   // 2^x
#if __has_builtin(__builtin_amdgcn_exp2f)
  return __builtin_amdgcn_exp2f(x);
#else
  return __expf(x * 0.69314718056f);
#endif
}

__device__ __forceinline__ f16x8 cvt8(float4 a, float4 b) {
  union { h16x2 h[4]; f16x8 v; } u;
  u.h[0] = __builtin_amdgcn_cvt_pkrtz(a.x, a.y);
  u.h[1] = __builtin_amdgcn_cvt_pkrtz(a.z, a.w);
  u.h[2] = __builtin_amdgcn_cvt_pkrtz(b.x, b.y);
  u.h[3] = __builtin_amdgcn_cvt_pkrtz(b.z, b.w);
  return u.v;
}

// scaled weight-load convert (init-time only)
__device__ __forceinline__ f16x8 cvt8s(const float* p, float s) {
  float4 a = *(const float4*)p;
  float4 b = *(const float4*)(p + 4);
  union { h16x2 h[4]; f16x8 v; } u;
  u.h[0] = __builtin_amdgcn_cvt_pkrtz(a.x * s, a.y * s);
  u.h[1] = __builtin_amdgcn_cvt_pkrtz(a.z * s, a.w * s);
  u.h[2] = __builtin_amdgcn_cvt_pkrtz(b.x * s, b.y * s);
  u.h[3] = __builtin_amdgcn_cvt_pkrtz(b.z * s, b.w * s);
  return u.v;
}

__device__ __forceinline__ f16x4 pack4(f32x2 a, f32x2 b) {
  union { h16x2 h2[2]; f16x4 v; } u;
  u.h2[0] = __builtin_amdgcn_cvt_pkrtz(a[0], a[1]);
  u.h2[1] = __builtin_amdgcn_cvt_pkrtz(b[0], b[1]);
  return u.v;
}

// Packed gate math for a pair of h-rows.  float2 ops -> v_pk_*_f32.
// Gate pre-scales are FOLDED INTO THE WEIGHTS/BIASES at load time:
//   aR,aZ arrive pre-multiplied by -log2(e)    -> ea = 2^aR = e^{-pre}
//   aXN,aHN arrive pre-multiplied by -2log2(e) -> my = aXN + r*aHN = -2log2e*y
// sigmoid pair shares one rcp; tanh(y) = (1-c)*rcp(1+c), c = 2^(-2log2e*y).
// Verified R7: absmax 0.0039 (unchanged).
__device__ __forceinline__ void gates_pair(f32x2 aR, f32x2 aZ, f32x2 aXN,
                                           f32x2 aHN, f32x2& hs) {
  f32x2 ea, eb;
  ea[0] = E2(aR[0]); ea[1] = E2(aR[1]);
  eb[0] = E2(aZ[0]); eb[1] = E2(aZ[1]);
  f32x2 pa = ea + 1.0f;
  f32x2 pb = eb + 1.0f;
  f32x2 prod = pa * pb;
  f32x2 inv;
  inv[0] = __builtin_amdgcn_rcpf(prod[0]);
  inv[1] = __builtin_amdgcn_rcpf(prod[1]);
  f32x2 rg = pb * inv;                 // sigmoid(r pre-act)
  f32x2 zg = pa * inv;                 // sigmoid(z pre-act)
  f32x2 my = aXN + rg * aHN;           // = -2log2e * (xn + r*hn)
  f32x2 c;
  c[0] = E2(my[0]); c[1] = E2(my[1]);
  f32x2 num = 1.0f - c;
  f32x2 den = 1.0f + c;
  f32x2 rin;
  rin[0] = __builtin_amdgcn_rcpf(den[0]);
  rin[1] = __builtin_amdgcn_rcpf(den[1]);
  f32x2 ng = num * rin;                // tanh(y)
  hs = zg * (hs - ng) + ng;
}

// B=4096, T=128, D=32, H=64.  R11: 16 batch / WG, 256 WGs, 1024 threads,
// 16 waves = 4 waves/SIMD inside ONE workgroup, with the VGPR budget
// PINNED via amdgpu_waves_per_eu(4,4).
//
// History: R2 (512,4) and R4 (1024,1) both had the allocator squeeze to
// the 64-VGPR occupancy step and SPILL the register-resident weights
// (WRITE_SIZE 16B -> 57-65MB) — every occupancy attempt so far was
// confounded by spills.  R4 did prove 16 waves co-reside (46% occupancy).
// amdgpu_waves_per_eu(4,4) sets the LLVM budget to exactly 512/4 = 128
// VGPR and (max=4) removes any reward for squeezing further: the ~84-VGPR
// kernel fits with zero spills at exactly the occupancy we want.
//
// Waves 0-7 (group A): layer 0, step t; wave sub=w&7 owns gate-rows
// [8*sub, 8*sub+8) (A-frag rows duplicated via l15&7; MFMA C-rows 8-15
// duplicate 0-7; lanes q>=2 carry inert mirrored state and never write).
// Waves 8-15 (group B): layer 1, step t-1, same split.  Per-wave
// instruction count is row-count-independent -> per-SIMD issue doubles,
// filling stall cycles (baseline: VALUBusy 48%, interval 1770cy of which
// >900cy is no-issue stall).
// Time loop unrolled x2 (parity/prefetch compile-time; runtime-indexed
// arrays -> scratch).  One LDS-only s_barrier per pipeline step.
// H LDS layout: h[k] for batch b at f16 offset ((k>>3)*16+b)*8 + (k&7)
//   -> B-frag for lane L, kfrag f = stride-1 ds_read_b128 at f*1024 + L*16.
__launch_bounds__(1024)
__attribute__((amdgpu_waves_per_eu(4, 4)))
__global__ void gru_fused(const float* __restrict__ x,
                          const float* __restrict__ Wih0, const float* __restrict__ Whh0,
                          const float* __restrict__ bih0, const float* __restrict__ bhh0,
                          const float* __restrict__ Wih1, const float* __restrict__ Whh1,
                          const float* __restrict__ bih1, const float* __restrict__ bhh1,
                          const float* __restrict__ fcw, const float* __restrict__ fcb,
                          float* __restrict__ out) {
  __shared__ f16 H0[2][1024];
  __shared__ f16 H1[2][1024];
  __shared__ float red[8][16];

  const int tid = threadIdx.x;
  const int wave = tid >> 6;          // 0..15
  const int lane = tid & 63;
  const int l15 = lane & 15;
  const int q = lane >> 4;            // 0..3; q>=2 = duplicate half
  const int sub = wave & 7;           // row-block [8*sub, 8*sub+8)
  const bool isB = wave >= 8;
  const int b0 = blockIdx.x * 16;

  for (int i = tid; i < 2048; i += 1024) {
    ((f16*)H0)[i] = (f16)0.0f;
    ((f16*)H1)[i] = (f16)0.0f;
  }

  const float SRZ = -1.44269504f;     // -log2(e)      folded into r,z rows
  const float SN  = -2.88539008f;     // -2*log2(e)    folded into n rows

  // ---- register-resident weight A-fragments: A[m=l15][k = kf*32 + q*8 + j]
  // Real rows are 8*sub + (l15&7); l15>=8 duplicates -> C rows 8-15 dup 0-7.
  f16x8 wAx[3];          // layer0 Wih (K=32)       — group A only
  f16x8 wAh[3][2];       // layer0 Whh (K=64)       — group A only
  f16x8 wBx[3][2];       // layer1 Wih (K=64)       — group B only
  f16x8 wBh[3][2];       // layer1 Whh (K=64)       — group B only
  f32x4 bR, bZ, bXN, bHN;
  float fw[4] = {0.f, 0.f, 0.f, 0.f};

  // Mirrored bias row for q>=2 keeps duplicate lanes bit-identical to q-2.
  const int ob = 8 * sub + 4 * (q & 1);

  if (!isB) {
#pragma unroll
    for (int g = 0; g < 3; ++g) {
      const float s = (g == 2) ? SN : SRZ;
      const int row = g * 64 + 8 * sub + (l15 & 7);
      wAx[g] = cvt8s(Wih0 + row * 32 + q * 8, s);
#pragma unroll
      for (int kf = 0; kf < 2; ++kf) {
        wAh[g][kf] = cvt8s(Whh0 + row * 64 + kf * 32 + q * 8, s);
      }
    }
#pragma unroll
    for (int r = 0; r < 4; ++r) {
      const int o = ob + r;
      bR[r]  = SRZ * (bih0[o] + bhh0[o]);
      bZ[r]  = SRZ * (bih0[64 + o] + bhh0[64 + o]);
      bXN[r] = SN * bih0[128 + o];
      bHN[r] = SN * bhh0[128 + o];
    }
  } else {
#pragma unroll
    for (int g = 0; g < 3; ++g) {
      const float s = (g == 2) ? SN : SRZ;
      const int row = g * 64 + 8 * sub + (l15 & 7);
#pragma unroll
      for (int kf = 0; kf < 2; ++kf) {
        wBx[g][kf] = cvt8s(Wih1 + row * 64 + kf * 32 + q * 8, s);
        wBh[g][kf] = cvt8s(Whh1 + row * 64 + kf * 32 + q * 8, s);
      }
    }
#pragma unroll
    for (int r = 0; r < 4; ++r) {
      const int o = ob + r;
      bR[r]  = SRZ * (bih1[o] + bhh1[o]);
      bZ[r]  = SRZ * (bih1[64 + o] + bhh1[64 + o]);
      bXN[r] = SN * bih1[128 + o];
      bHN[r] = SN * bhh1[128 + o];
      fw[r] = (q < 2) ? fcw[o] : 0.f;   // duplicate lanes contribute 0 to fc
    }
  }
  const float fcb0 = fcb[0];

  f32x2 hs01 = {0.f, 0.f}, hs23 = {0.f, 0.f};  // this lane's 4 h rows (own layer)

  const bool wr = (q < 2);                                  // real-row lanes
  const int wk0 = ob;                                       // lane's h-row base
  const int widx = ((wk0 >> 3) * 16 + l15) * 8 + (wk0 & 7); // f16 offset of its b64 store

  // layer-0 step: read H0r, consume x frag, write H0w (q<2 lanes only)
  auto stepA = [&](const f16* H0r, f16* H0w, float4 xav, float4 xbv) {
    const f16x8 xf = cvt8(xav, xbv);
    const f16x8 h0f0 = *(const f16x8*)&H0r[lane * 8];
    const f16x8 h0f1 = *(const f16x8*)&H0r[512 + lane * 8];
    f32x4 aR  = MFMA16(wAx[0], xf, bR);
    f32x4 aZ  = MFMA16(wAx[1], xf, bZ);
    f32x4 aXN = MFMA16(wAx[2], xf, bXN);
    f32x4 aHN = MFMA16(wAh[2][0], h0f0, bHN);
    aR  = MFMA16(wAh[0][0], h0f0, aR);
    aZ  = MFMA16(wAh[1][0], h0f0, aZ);
    aR  = MFMA16(wAh[0][1], h0f1, aR);
    aZ  = MFMA16(wAh[1][1], h0f1, aZ);
    aHN = MFMA16(wAh[2][1], h0f1, aHN);
    gates_pair(f32x2{aR[0], aR[1]}, f32x2{aZ[0], aZ[1]},
               f32x2{aXN[0], aXN[1]}, f32x2{aHN[0], aHN[1]}, hs01);
    gates_pair(f32x2{aR[2], aR[3]}, f32x2{aZ[2], aZ[3]},
               f32x2{aXN[2], aXN[3]}, f32x2{aHN[2], aHN[3]}, hs23);
    if (wr) *(f16x4*)&H0w[widx] = pack4(hs01, hs23);
  };

  // layer-1 step: read h0 from H0r, own state from H1r, write H1w (q<2 only)
  auto stepB = [&](const f16* H0r, const f16* H1r, f16* H1w) {
    const f16x8 g0 = *(const f16x8*)&H0r[lane * 8];
    const f16x8 g1 = *(const f16x8*)&H0r[512 + lane * 8];
    const f16x8 h1f0 = *(const f16x8*)&H1r[lane * 8];
    const f16x8 h1f1 = *(const f16x8*)&H1r[512 + lane * 8];
    f32x4 aR  = MFMA16(wBx[0][0], g0, bR);
    f32x4 aZ  = MFMA16(wBx[1][0], g0, bZ);
    f32x4 aXN = MFMA16(wBx[2][0], g0, bXN);
    aR  = MFMA16(wBx[0][1], g1, aR);
    aZ  = MFMA16(wBx[1][1], g1, aZ);
    aXN = MFMA16(wBx[2][1], g1, aXN);
    f32x4 aHN = MFMA16(wBh[2][0], h1f0, bHN);
    aR  = MFMA16(wBh[0][0], h1f0, aR);
    aZ  = MFMA16(wBh[1][0], h1f0, aZ);
    aR  = MFMA16(wBh[0][1], h1f1, aR);
    aZ  = MFMA16(wBh[1][1], h1f1, aZ);
    aHN = MFMA16(wBh[2][1], h1f1, aHN);
    gates_pair(f32x2{aR[0], aR[1]}, f32x2{aZ[0], aZ[1]},
               f32x2{aXN[0], aXN[1]}, f32x2{aHN[0], aHN[1]}, hs01);
    gates_pair(f32x2{aR[2], aR[3]}, f32x2{aZ[2], aZ[3]},
               f32x2{aXN[2], aXN[3]}, f32x2{aHN[2], aHN[3]}, hs23);
    if (wr) *(f16x4*)&H1w[widx] = pack4(hs01, hs23);
  };

  __syncthreads();

  // x B-frag source (group A waves): lane (l15,q) reads x[b0+l15][t][q*8..].
  // All 8 A-waves load the same lines; L1 absorbs the redundancy.
  const float* xbase = x + (size_t)(b0 + l15) * 4096 + q * 8;
  float4 xa0, xb0, xa1, xb1;
  if (!isB) {
    xa0 = *(const float4*)xbase;
    xb0 = *(const float4*)(xbase + 4);
    xa1 = *(const float4*)(xbase + 32);
    xb1 = *(const float4*)(xbase + 36);
  }

  for (int t = 0; t < 128; t += 2) {
    // ---- pipeline iteration t (parity 0): A step t, B step t-1
    if (!isB) {
      const float4 cxa = xa0, cxb = xb0;
      if (t + 2 < 128) {
        const float* xp = xbase + (t + 2) * 32;
        xa0 = *(const float4*)xp;
        xb0 = *(const float4*)(xp + 4);
      }
      stepA(H0[0], H0[1], cxa, cxb);
    } else if (t > 0) {
      stepB(H0[0], H1[0], H1[1]);
    }
    LDS_BARRIER();

    // ---- pipeline iteration t+1 (parity 1): A step t+1, B step t
    if (!isB) {
      const float4 cxa = xa1, cxb = xb1;
      if (t + 3 < 128) {
        const float* xp = xbase + (t + 3) * 32;
        xa1 = *(const float4*)xp;
        xb1 = *(const float4*)(xp + 4);
      }
      stepA(H0[1], H0[0], cxa, cxb);
    } else {
      stepB(H0[1], H1[1], H1[0]);
    }
    LDS_BARRIER();
  }
  // ---- pipeline iteration t=128 (parity 0): B step 127 only
  if (isB) stepB(H0[0], H1[0], H1[1]);

  // ---- fc: out[b] = sum_i h1[i]*fcw[i] + fcb   (group B holds h1(127);
  //      q>=2 duplicate lanes have fw=0 so they contribute nothing)
  if (isB) {
    float partial = fw[0] * hs01[0] + fw[1] * hs01[1] + fw[2] * hs23[0] + fw[3] * hs23[1];
    partial += __shfl_down(partial, 16, 64);
    partial += __shfl_down(partial, 32, 64);
    if (lane < 16) red[sub][l15] = partial;
  }
  __syncthreads();
  if (tid < 16) {
    float s = red[0][tid] + red[1][tid] + red[2][tid] + red[3][tid] +
              red[4][tid] + red[5][tid] + red[6][tid] + red[7][tid];
    out[b0 + tid] = s + fcb0;
  }
}

extern "C" void kernel_launch(void* const* d_in, const int* in_sizes, int n_in,
                              void* d_out, int out_size, void* d_ws, size_t ws_size,
                              hipStream_t stream) {
  (void)in_sizes; (void)n_in; (void)out_size; (void)d_ws; (void)ws_size;
  const float* x    = (const float*)d_in[0];
  const float* Wih0 = (const float*)d_in[1];
  const float* Whh0 = (const float*)d_in[2];
  const float* bih0 = (const float*)d_in[3];
  const float* bhh0 = (const float*)d_in[4];
  const float* Wih1 = (const float*)d_in[5];
  const float* Whh1 = (const float*)d_in[6];
  const float* bih1 = (const float*)d_in[7];
  const float* bhh1 = (const float*)d_in[8];
  const float* fcw  = (const float*)d_in[9];
  const float* fcb  = (const float*)d_in[10];
  float* out = (float*)d_out;

  gru_fused<<<256, 1024, 0, stream>>>(x, Wih0, Whh0, bih0, bhh0,
                                      Wih1, Whh1, bih1, bhh1, fcw, fcb, out);
}

// Round 6
// 194.152 us; speedup vs baseline: 2.3357x; 2.3252x over previous
//
#include <hip/hip_runtime.h>

typedef _Float16 f16;
typedef f16 f16x8 __attribute__((ext_vector_type(8)));
typedef f16 f16x4 __attribute__((ext_vector_type(4)));
typedef __fp16 h16x2 __attribute__((ext_vector_type(2)));   // cvt_pkrtz native type
typedef float f32x4 __attribute__((ext_vector_type(4)));
typedef float f32x2 __attribute__((ext_vector_type(2)));

#define MFMA16(A, B, C) __builtin_amdgcn_mfma_f32_16x16x32_f16((A), (B), (C), 0, 0, 0)

// Barrier WITHOUT vmcnt drain: only LDS (lgkmcnt) must be visible across it.
#define LDS_BARRIER() asm volatile("s_waitcnt lgkmcnt(0)\n\ts_barrier" ::: "memory")

__device__ __forceinline__ float E2(float x) {   // 2^x
#if __has_builtin(__builtin_amdgcn_exp2f)
  return __builtin_amdgcn_exp2f(x);
#else
  return __expf(x * 0.69314718056f);
#endif
}

__device__ __forceinline__ f16x8 cvt8(float4 a, float4 b) {
  union { h16x2 h[4]; f16x8 v; } u;
  u.h[0] = __builtin_amdgcn_cvt_pkrtz(a.x, a.y);
  u.h[1] = __builtin_amdgcn_cvt_pkrtz(a.z, a.w);
  u.h[2] = __builtin_amdgcn_cvt_pkrtz(b.x, b.y);
  u.h[3] = __builtin_amdgcn_cvt_pkrtz(b.z, b.w);
  return u.v;
}

// scaled weight-load convert (init-time only)
__device__ __forceinline__ f16x8 cvt8s(const float* p, float s) {
  float4 a = *(const float4*)p;
  float4 b = *(const float4*)(p + 4);
  union { h16x2 h[4]; f16x8 v; } u;
  u.h[0] = __builtin_amdgcn_cvt_pkrtz(a.x * s, a.y * s);
  u.h[1] = __builtin_amdgcn_cvt_pkrtz(a.z * s, a.w * s);
  u.h[2] = __builtin_amdgcn_cvt_pkrtz(b.x * s, b.y * s);
  u.h[3] = __builtin_amdgcn_cvt_pkrtz(b.z * s, b.w * s);
  return u.v;
}

__device__ __forceinline__ f16x4 pack4(f32x2 a, f32x2 b) {
  union { h16x2 h2[2]; f16x4 v; } u;
  u.h2[0] = __builtin_amdgcn_cvt_pkrtz(a[0], a[1]);
  u.h2[1] = __builtin_amdgcn_cvt_pkrtz(b[0], b[1]);
  return u.v;
}

// Packed gate math for a pair of h-rows.  float2 ops -> v_pk_*_f32.
// Gate pre-scales FOLDED INTO WEIGHTS/BIASES at load time (R1-verified):
//   aR,aZ arrive pre-multiplied by -log2(e)    -> ea = 2^aR = e^{-pre}
//   aXN,aHN arrive pre-multiplied by -2log2(e) -> my = aXN + r*aHN = -2log2e*y
// sigmoid pair shares one rcp; tanh(y) = (1-c)*rcp(1+c), c = 2^(-2log2e*y).
__device__ __forceinline__ void gates_pair(f32x2 aR, f32x2 aZ, f32x2 aXN,
                                           f32x2 aHN, f32x2& hs) {
  f32x2 ea, eb;
  ea[0] = E2(aR[0]); ea[1] = E2(aR[1]);
  eb[0] = E2(aZ[0]); eb[1] = E2(aZ[1]);
  f32x2 pa = ea + 1.0f;
  f32x2 pb = eb + 1.0f;
  f32x2 prod = pa * pb;
  f32x2 inv;
  inv[0] = __builtin_amdgcn_rcpf(prod[0]);
  inv[1] = __builtin_amdgcn_rcpf(prod[1]);
  f32x2 rg = pb * inv;                 // sigmoid(r pre-act)
  f32x2 zg = pa * inv;                 // sigmoid(z pre-act)
  f32x2 my = aXN + rg * aHN;           // = -2log2e * (xn + r*hn)
  f32x2 c;
  c[0] = E2(my[0]); c[1] = E2(my[1]);
  f32x2 num = 1.0f - c;
  f32x2 den = 1.0f + c;
  f32x2 rin;
  rin[0] = __builtin_amdgcn_rcpf(den[0]);
  rin[1] = __builtin_amdgcn_rcpf(den[1]);
  f32x2 ng = num * rin;                // tanh(y)
  hs = zg * (hs - ng) + ng;
}

// B=4096, T=128, D=32, H=64.  R12: 16 REAL batches / WG, 256 WGs,
// **768 threads = 12 waves = 3 waves/SIMD in one workgroup**.
//
// Config map from R2-R5: (512,2)=84 VGPR/no-spill/2 waves-per-SIMD (95us);
// any config implying >=4 waves/EU pins arch-VGPRs to 64 (gfx950 unified
// file splits the 512-reg budget arch/accum at high occupancy) -> weight
// fragments spill to scratch -> 4x regression.  2nd co-resident WG at 80
// VGPR: scheduler refuses.  3 waves/EU is the untried point: budget
// 512/3=170 arch-side ~96+, our ~84-reg kernel fits with margin, and
// per-SIMD independent chains go 2 -> 3 (+50% issue into stall cycles).
//
// 64 h-rows can't split 6+6, so the 12 waves are ASYMMETRIC:
//   waves 0-7  (group A, layer 0, step t):   8-row blocks via the
//     R4-verified l15&7 row-duplication (A rows 8-15 dup 0-7, C rows 8-15
//     dup; lanes q>=2 inert, bias mirrored via q&1; writes predicated).
//     All 16 batch-cols REAL.
//   waves 8-11 (group B, layer 1, step t-1): baseline 16-row blocks.
// Per SIMD: 2 A-waves (9 MFMA) + 1 B-wave (12 MFMA) — balanced.
//
// Time loop unrolled x2 (parity/prefetch compile-time).  One LDS-only
// s_barrier per pipeline step.
// H LDS layout: h[k] for batch b at f16 offset ((k>>3)*16+b)*8 + (k&7)
//   -> B-frag for lane L, kfrag f = stride-1 ds_read_b128 at f*1024 + L*16.
__launch_bounds__(768)
__attribute__((amdgpu_waves_per_eu(3, 3)))
__global__ void gru_fused(const float* __restrict__ x,
                          const float* __restrict__ Wih0, const float* __restrict__ Whh0,
                          const float* __restrict__ bih0, const float* __restrict__ bhh0,
                          const float* __restrict__ Wih1, const float* __restrict__ Whh1,
                          const float* __restrict__ bih1, const float* __restrict__ bhh1,
                          const float* __restrict__ fcw, const float* __restrict__ fcb,
                          float* __restrict__ out) {
  __shared__ f16 H0[2][1024];
  __shared__ f16 H1[2][1024];
  __shared__ float red[4][16];

  const int tid = threadIdx.x;
  const int wave = tid >> 6;          // 0..11
  const int lane = tid & 63;
  const int l15 = lane & 15;
  const int q = lane >> 4;            // 0..3
  const bool isB = wave >= 8;
  const int b0 = blockIdx.x * 16;

  for (int i = tid; i < 2048; i += 768) {
    ((f16*)H0)[i] = (f16)0.0f;
    ((f16*)H1)[i] = (f16)0.0f;
  }

  const float SRZ = -1.44269504f;     // -log2(e)      folded into r,z rows
  const float SN  = -2.88539008f;     // -2*log2(e)    folded into n rows

  // ---- register-resident weight A-fragments: A[m=l15..][k = kf*32 + q*8 + j]
  f16x8 wAx[3];          // layer0 Wih (K=32)       — group A only
  f16x8 wAh[3][2];       // layer0 Whh (K=64)       — group A only
  f16x8 wBx[3][2];       // layer1 Wih (K=64)       — group B only
  f16x8 wBh[3][2];       // layer1 Whh (K=64)       — group B only
  f32x4 bR, bZ, bXN, bHN;
  float fw[4] = {0.f, 0.f, 0.f, 0.f};

  int wk0;   // this lane's first h-row (own layer)
  bool wr;   // does this lane write its rows?

  if (!isB) {
    // ---- A: 8-row block [8*sub, 8*sub+8), rows duplicated via l15&7
    const int sub = wave;             // 0..7
    wk0 = 8 * sub + 4 * (q & 1);      // bias/state row base (mirrored q>=2)
    wr = (q < 2);
#pragma unroll
    for (int g = 0; g < 3; ++g) {
      const float s = (g == 2) ? SN : SRZ;
      const int row = g * 64 + 8 * sub + (l15 & 7);
      wAx[g] = cvt8s(Wih0 + row * 32 + q * 8, s);
#pragma unroll
      for (int kf = 0; kf < 2; ++kf) {
        wAh[g][kf] = cvt8s(Whh0 + row * 64 + kf * 32 + q * 8, s);
      }
    }
#pragma unroll
    for (int r = 0; r < 4; ++r) {
      const int o = wk0 + r;
      bR[r]  = SRZ * (bih0[o] + bhh0[o]);
      bZ[r]  = SRZ * (bih0[64 + o] + bhh0[64 + o]);
      bXN[r] = SN * bih0[128 + o];
      bHN[r] = SN * bhh0[128 + o];
    }
  } else {
    // ---- B: baseline 16-row block [16*wa, 16*wa+16), all lanes real
    const int wa = wave - 8;          // 0..3
    wk0 = 16 * wa + 4 * q;
    wr = true;
#pragma unroll
    for (int g = 0; g < 3; ++g) {
      const float s = (g == 2) ? SN : SRZ;
      const int row = g * 64 + 16 * wa + l15;
#pragma unroll
      for (int kf = 0; kf < 2; ++kf) {
        wBx[g][kf] = cvt8s(Wih1 + row * 64 + kf * 32 + q * 8, s);
        wBh[g][kf] = cvt8s(Whh1 + row * 64 + kf * 32 + q * 8, s);
      }
    }
#pragma unroll
    for (int r = 0; r < 4; ++r) {
      const int o = wk0 + r;
      bR[r]  = SRZ * (bih1[o] + bhh1[o]);
      bZ[r]  = SRZ * (bih1[64 + o] + bhh1[64 + o]);
      bXN[r] = SN * bih1[128 + o];
      bHN[r] = SN * bhh1[128 + o];
      fw[r] = fcw[o];
    }
  }
  const float fcb0 = fcb[0];

  f32x2 hs01 = {0.f, 0.f}, hs23 = {0.f, 0.f};  // this lane's 4 h rows (own layer)

  const int widx = ((wk0 >> 3) * 16 + l15) * 8 + (wk0 & 7); // f16 off of b64 store

  // layer-0 step: read H0r, consume x frag, write H0w (wr lanes only)
  auto stepA = [&](const f16* H0r, f16* H0w, float4 xav, float4 xbv) {
    const f16x8 xf = cvt8(xav, xbv);
    const f16x8 h0f0 = *(const f16x8*)&H0r[lane * 8];
    const f16x8 h0f1 = *(const f16x8*)&H0r[512 + lane * 8];
    f32x4 aR  = MFMA16(wAx[0], xf, bR);
    f32x4 aZ  = MFMA16(wAx[1], xf, bZ);
    f32x4 aXN = MFMA16(wAx[2], xf, bXN);
    f32x4 aHN = MFMA16(wAh[2][0], h0f0, bHN);
    aR  = MFMA16(wAh[0][0], h0f0, aR);
    aZ  = MFMA16(wAh[1][0], h0f0, aZ);
    aR  = MFMA16(wAh[0][1], h0f1, aR);
    aZ  = MFMA16(wAh[1][1], h0f1, aZ);
    aHN = MFMA16(wAh[2][1], h0f1, aHN);
    gates_pair(f32x2{aR[0], aR[1]}, f32x2{aZ[0], aZ[1]},
               f32x2{aXN[0], aXN[1]}, f32x2{aHN[0], aHN[1]}, hs01);
    gates_pair(f32x2{aR[2], aR[3]}, f32x2{aZ[2], aZ[3]},
               f32x2{aXN[2], aXN[3]}, f32x2{aHN[2], aHN[3]}, hs23);
    if (wr) *(f16x4*)&H0w[widx] = pack4(hs01, hs23);
  };

  // layer-1 step: read h0 from H0r, own state from H1r, write H1w
  auto stepB = [&](const f16* H0r, const f16* H1r, f16* H1w) {
    const f16x8 g0 = *(const f16x8*)&H0r[lane * 8];
    const f16x8 g1 = *(const f16x8*)&H0r[512 + lane * 8];
    const f16x8 h1f0 = *(const f16x8*)&H1r[lane * 8];
    const f16x8 h1f1 = *(const f16x8*)&H1r[512 + lane * 8];
    f32x4 aR  = MFMA16(wBx[0][0], g0, bR);
    f32x4 aZ  = MFMA16(wBx[1][0], g0, bZ);
    f32x4 aXN = MFMA16(wBx[2][0], g0, bXN);
    aR  = MFMA16(wBx[0][1], g1, aR);
    aZ  = MFMA16(wBx[1][1], g1, aZ);
    aXN = MFMA16(wBx[2][1], g1, aXN);
    f32x4 aHN = MFMA16(wBh[2][0], h1f0, bHN);
    aR  = MFMA16(wBh[0][0], h1f0, aR);
    aZ  = MFMA16(wBh[1][0], h1f0, aZ);
    aR  = MFMA16(wBh[0][1], h1f1, aR);
    aZ  = MFMA16(wBh[1][1], h1f1, aZ);
    aHN = MFMA16(wBh[2][1], h1f1, aHN);
    gates_pair(f32x2{aR[0], aR[1]}, f32x2{aZ[0], aZ[1]},
               f32x2{aXN[0], aXN[1]}, f32x2{aHN[0], aHN[1]}, hs01);
    gates_pair(f32x2{aR[2], aR[3]}, f32x2{aZ[2], aZ[3]},
               f32x2{aXN[2], aXN[3]}, f32x2{aHN[2], aHN[3]}, hs23);
    if (wr) *(f16x4*)&H1w[widx] = pack4(hs01, hs23);
  };

  __syncthreads();

  // x B-frag source (group A waves): lane (l15,q) reads x[b0+l15][t][q*8..].
  // 16 real batch-cols; all 8 A-waves read the same lines (L1 absorbs).
  const float* xbase = x + (size_t)(b0 + l15) * 4096 + q * 8;
  float4 xa0, xb0, xa1, xb1;
  if (!isB) {
    xa0 = *(const float4*)xbase;
    xb0 = *(const float4*)(xbase + 4);
    xa1 = *(const float4*)(xbase + 32);
    xb1 = *(const float4*)(xbase + 36);
  }

  for (int t = 0; t < 128; t += 2) {
    // ---- pipeline iteration t (parity 0): A step t, B step t-1
    if (!isB) {
      const float4 cxa = xa0, cxb = xb0;
      if (t + 2 < 128) {
        const float* xp = xbase + (t + 2) * 32;
        xa0 = *(const float4*)xp;
        xb0 = *(const float4*)(xp + 4);
      }
      stepA(H0[0], H0[1], cxa, cxb);
    } else if (t > 0) {
      stepB(H0[0], H1[0], H1[1]);
    }
    LDS_BARRIER();

    // ---- pipeline iteration t+1 (parity 1): A step t+1, B step t
    if (!isB) {
      const float4 cxa = xa1, cxb = xb1;
      if (t + 3 < 128) {
        const float* xp = xbase + (t + 3) * 32;
        xa1 = *(const float4*)xp;
        xb1 = *(const float4*)(xp + 4);
      }
      stepA(H0[1], H0[0], cxa, cxb);
    } else {
      stepB(H0[1], H1[1], H1[0]);
    }
    LDS_BARRIER();
  }
  // ---- pipeline iteration t=128 (parity 0): B step 127 only
  if (isB) stepB(H0[0], H1[0], H1[1]);

  // ---- fc: out[b] = sum_i h1[i]*fcw[i] + fcb   (group B holds h1(127))
  if (isB) {
    float partial = fw[0] * hs01[0] + fw[1] * hs01[1] + fw[2] * hs23[0] + fw[3] * hs23[1];
    partial += __shfl_down(partial, 16, 64);
    partial += __shfl_down(partial, 32, 64);
    if (lane < 16) red[wave - 8][l15] = partial;
  }
  __syncthreads();
  if (tid < 16) out[b0 + tid] = red[0][tid] + red[1][tid] + red[2][tid] + red[3][tid] + fcb0;
}

extern "C" void kernel_launch(void* const* d_in, const int* in_sizes, int n_in,
                              void* d_out, int out_size, void* d_ws, size_t ws_size,
                              hipStream_t stream) {
  (void)in_sizes; (void)n_in; (void)out_size; (void)d_ws; (void)ws_size;
  const float* x    = (const float*)d_in[0];
  const float* Wih0 = (const float*)d_in[1];
  const float* Whh0 = (const float*)d_in[2];
  const float* bih0 = (const float*)d_in[3];
  const float* bhh0 = (const float*)d_in[4];
  const float* Wih1 = (const float*)d_in[5];
  const float* Whh1 = (const float*)d_in[6];
  const float* bih1 = (const float*)d_in[7];
  const float* bhh1 = (const float*)d_in[8];
  const float* fcw  = (const float*)d_in[9];
  const float* fcb  = (const float*)d_in[10];
  float* out = (float*)d_out;

  gru_fused<<<256, 768, 0, stream>>>(x, Wih0, Whh0, bih0, bhh0,
                                     Wih1, Whh1, bih1, bhh1, fcw, fcb, out);
}

// Round 7
// 179.610 us; speedup vs baseline: 2.5248x; 1.0810x over previous
//
#include <hip/hip_runtime.h>

typedef _Float16 f16;
typedef f16 f16x8 __attribute__((ext_vector_type(8)));
typedef f16 f16x4 __attribute__((ext_vector_type(4)));
typedef __fp16 h16x2 __attribute__((ext_vector_type(2)));   // cvt_pkrtz native type
typedef float f32x4 __attribute__((ext_vector_type(4)));
typedef float f32x2 __attribute__((ext_vector_type(2)));

#define MFMA16(A, B, C) __builtin_amdgcn_mfma_f32_16x16x32_f16((A), (B), (C), 0, 0, 0)

// Barrier WITHOUT vmcnt drain: only LDS (lgkmcnt) must be visible across it.
// (R6-legacy: LDS flag sync is WORSE than s_barrier; __syncthreads would
// drain vmcnt and serialize the in-flight x prefetch.)
#define LDS_BARRIER() asm volatile("s_waitcnt lgkmcnt(0)\n\ts_barrier" ::: "memory")

__device__ __forceinline__ float E2(float x) {   // 2^x
#if __has_builtin(__builtin_amdgcn_exp2f)
  return __builtin_amdgcn_exp2f(x);
#else
  return __expf(x * 0.69314718056f);
#endif
}
__device__ __forceinline__ float RCP(float x) { return __builtin_amdgcn_rcpf(x); }

__device__ __forceinline__ f16x8 cvt8(float4 a, float4 b) {
  union { h16x2 h[4]; f16x8 v; } u;
  u.h[0] = __builtin_amdgcn_cvt_pkrtz(a.x, a.y);
  u.h[1] = __builtin_amdgcn_cvt_pkrtz(a.z, a.w);
  u.h[2] = __builtin_amdgcn_cvt_pkrtz(b.x, b.y);
  u.h[3] = __builtin_amdgcn_cvt_pkrtz(b.z, b.w);
  return u.v;
}

// scaled weight-load convert (init-time only)
__device__ __forceinline__ f16x8 cvt8s(const float* p, float s) {
  float4 a = *(const float4*)p;
  float4 b = *(const float4*)(p + 4);
  union { h16x2 h[4]; f16x8 v; } u;
  u.h[0] = __builtin_amdgcn_cvt_pkrtz(a.x * s, a.y * s);
  u.h[1] = __builtin_amdgcn_cvt_pkrtz(a.z * s, a.w * s);
  u.h[2] = __builtin_amdgcn_cvt_pkrtz(b.x * s, b.y * s);
  u.h[3] = __builtin_amdgcn_cvt_pkrtz(b.z * s, b.w * s);
  return u.v;
}

__device__ __forceinline__ f16x4 pack4(float a0, float a1, float a2, float a3) {
  union { h16x2 h2[2]; f16x4 v; } u;
  u.h2[0] = __builtin_amdgcn_cvt_pkrtz(a0, a1);
  u.h2[1] = __builtin_amdgcn_cvt_pkrtz(a2, a3);
  return u.v;
}

// ---- R7 gate math: 4 rows at once, CROSS-ROW SHARED rcp (trans-issue cut).
// Pre-scales folded into weights/biases (R1-verified):
//   aR,aZ pre-multiplied by -log2(e); aXN,aHN pre-multiplied by -2log2(e).
// sigmoid4: 8 E2 + 2 rcp for 4 rows' r,z (was 8 E2 + 4 rcp).
//   per row pair p,q: inv = rcp(prod_p*prod_q); 1/prod_p = prod_q*inv.
//   ranges: prod <= 2^62, product of two <= 2^124 < f32 max; rcp >= 2^-124
//   still normal.  rel err ~1e-6 — invisible under f16 state rounding.
// tanh4: 4 E2 + 2 rcp (was 4 E2 + 4 rcp), same sharing on (1+c).
__device__ __forceinline__ void sigmoid4(f32x4 aR, f32x4 aZ,
                                         f32x4& rg, f32x4& zg) {
  f32x4 ea, eb;
  ea[0] = E2(aR[0]); ea[1] = E2(aR[1]); ea[2] = E2(aR[2]); ea[3] = E2(aR[3]);
  eb[0] = E2(aZ[0]); eb[1] = E2(aZ[1]); eb[2] = E2(aZ[2]); eb[3] = E2(aZ[3]);
  f32x4 pa = ea + 1.0f;
  f32x4 pb = eb + 1.0f;
  f32x4 prod = pa * pb;
  float i01 = RCP(prod[0] * prod[1]);
  float i23 = RCP(prod[2] * prod[3]);
  f32x4 invv;
  invv[0] = prod[1] * i01; invv[1] = prod[0] * i01;
  invv[2] = prod[3] * i23; invv[3] = prod[2] * i23;   // = 1/prod[i]
  rg = pb * invv;                  // sigmoid(r pre-act)
  zg = pa * invv;                  // sigmoid(z pre-act)
}
__device__ __forceinline__ f32x4 tanh4(f32x4 my) {     // my = -2log2e * y
  f32x4 c;
  c[0] = E2(my[0]); c[1] = E2(my[1]); c[2] = E2(my[2]); c[3] = E2(my[3]);
  f32x4 num = 1.0f - c;
  f32x4 den = 1.0f + c;
  float j01 = RCP(den[0] * den[1]);
  float j23 = RCP(den[2] * den[3]);
  f32x4 dv;
  dv[0] = den[1] * j01; dv[1] = den[0] * j01;
  dv[2] = den[3] * j23; dv[3] = den[2] * j23;          // = 1/den[i]
  return num * dv;                 // tanh(y)
}

// B=4096, T=128, D=32, H=64.  16 batch / WG, 8 waves — the proven 95us
// baseline structure (R1-R6 established: 2 waves/SIMD of NON-duplicated
// work is the right shape; every occupancy-raising variant either spilled
// the weights (64-VGPR arch cap at >=4 waves/EU), was refused co-residency,
// or added duplicated issue (R6: +50% work -> +27% interval).  The interval
// is issue-bound at the margin; R7 therefore CUTS issued work:
//   (a) cross-row shared rcp: 8 -> 4 rcp/wave-step  (-64 cy trans issue)
//   (b) MFMA reorder: aR/aZ chains complete FIRST, sigmoid E2 burst issues
//       while aXN/aHN MFMAs run on the matrix pipe (trans/matrix overlap)
//   (c) s_setprio(1) around MFMA clusters (role-diverse waves per SIMD)
// plus the R1-verified weight pre-scale fold.
//
// Waves 0-3 (group A): layer 0, step t.   Waves 4-7 (group B): layer 1, t-1.
// Time loop unrolled x2 (parity/prefetch compile-time).  One LDS-only
// s_barrier per pipeline step.
// H LDS layout: h[k] for batch b at f16 offset ((k>>3)*16+b)*8 + (k&7)
//   -> B-frag for lane L, kfrag f = stride-1 ds_read_b128 at f*1024 + L*16.
__launch_bounds__(512, 2)
__global__ void gru_fused(const float* __restrict__ x,
                          const float* __restrict__ Wih0, const float* __restrict__ Whh0,
                          const float* __restrict__ bih0, const float* __restrict__ bhh0,
                          const float* __restrict__ Wih1, const float* __restrict__ Whh1,
                          const float* __restrict__ bih1, const float* __restrict__ bhh1,
                          const float* __restrict__ fcw, const float* __restrict__ fcb,
                          float* __restrict__ out) {
  __shared__ f16 H0[2][1024];
  __shared__ f16 H1[2][1024];
  __shared__ float red[4][16];

  const int tid = threadIdx.x;
  const int wave = tid >> 6;
  const int lane = tid & 63;
  const int l15 = lane & 15;
  const int q = lane >> 4;
  const int wa = wave & 3;
  const bool isB = wave >= 4;
  const int b0 = blockIdx.x * 16;

  for (int i = tid; i < 2048; i += 512) {
    ((f16*)H0)[i] = (f16)0.0f;
    ((f16*)H1)[i] = (f16)0.0f;
  }

  const float SRZ = -1.44269504f;     // -log2(e)      folded into r,z rows
  const float SN  = -2.88539008f;     // -2*log2(e)    folded into n rows

  // ---- register-resident weight A-fragments: A[m=l15][k = kf*32 + q*8 + j]
  f16x8 wAx[3];          // layer0 Wih (K=32)       — group A only
  f16x8 wAh[3][2];       // layer0 Whh (K=64)       — group A only
  f16x8 wBx[3][2];       // layer1 Wih (K=64)       — group B only
  f16x8 wBh[3][2];       // layer1 Whh (K=64)       — group B only
  f32x4 bR, bZ, bXN, bHN;
  float fw[4] = {0.f, 0.f, 0.f, 0.f};

  if (!isB) {
#pragma unroll
    for (int g = 0; g < 3; ++g) {
      const float s = (g == 2) ? SN : SRZ;
      const int row = g * 64 + 16 * wa + l15;
      wAx[g] = cvt8s(Wih0 + row * 32 + q * 8, s);
#pragma unroll
      for (int kf = 0; kf < 2; ++kf) {
        wAh[g][kf] = cvt8s(Whh0 + row * 64 + kf * 32 + q * 8, s);
      }
    }
#pragma unroll
    for (int r = 0; r < 4; ++r) {
      const int o = 16 * wa + 4 * q + r;
      bR[r]  = SRZ * (bih0[o] + bhh0[o]);
      bZ[r]  = SRZ * (bih0[64 + o] + bhh0[64 + o]);
      bXN[r] = SN * bih0[128 + o];
      bHN[r] = SN * bhh0[128 + o];
    }
  } else {
#pragma unroll
    for (int g = 0; g < 3; ++g) {
      const float s = (g == 2) ? SN : SRZ;
      const int row = g * 64 + 16 * wa + l15;
#pragma unroll
      for (int kf = 0; kf < 2; ++kf) {
        wBx[g][kf] = cvt8s(Wih1 + row * 64 + kf * 32 + q * 8, s);
        wBh[g][kf] = cvt8s(Whh1 + row * 64 + kf * 32 + q * 8, s);
      }
    }
#pragma unroll
    for (int r = 0; r < 4; ++r) {
      const int o = 16 * wa + 4 * q + r;
      bR[r]  = SRZ * (bih1[o] + bhh1[o]);
      bZ[r]  = SRZ * (bih1[64 + o] + bhh1[64 + o]);
      bXN[r] = SN * bih1[128 + o];
      bHN[r] = SN * bhh1[128 + o];
      fw[r] = fcw[o];
    }
  }
  const float fcb0 = fcb[0];

  f32x4 hs = {0.f, 0.f, 0.f, 0.f};   // this lane's 4 h rows (own layer)

  const int wk0 = 16 * wa + 4 * q;                          // lane's 4 h-row base
  const int widx = ((wk0 >> 3) * 16 + l15) * 8 + (wk0 & 7); // f16 offset of b64 store

  // layer-0 step: read H0r, consume x frag, write H0w.
  // MFMA order: R,Z chains first -> sigmoid E2 burst -> XN/HN MFMAs issue
  // underneath the trans burst -> tanh + update.
  auto stepA = [&](const f16* H0r, f16* H0w, float4 xav, float4 xbv) {
    const f16x8 h0f0 = *(const f16x8*)&H0r[lane * 8];
    const f16x8 h0f1 = *(const f16x8*)&H0r[512 + lane * 8];
    const f16x8 xf = cvt8(xav, xbv);
    __builtin_amdgcn_s_setprio(1);
    f32x4 aR = MFMA16(wAx[0], xf, bR);
    f32x4 aZ = MFMA16(wAx[1], xf, bZ);
    aR = MFMA16(wAh[0][0], h0f0, aR);
    aZ = MFMA16(wAh[1][0], h0f0, aZ);
    aR = MFMA16(wAh[0][1], h0f1, aR);
    aZ = MFMA16(wAh[1][1], h0f1, aZ);
    __builtin_amdgcn_s_setprio(0);
    f32x4 rg, zg;
    sigmoid4(aR, aZ, rg, zg);          // trans burst...
    f32x4 aXN = MFMA16(wAx[2], xf, bXN);            // ...overlaps these MFMAs
    f32x4 aHN = MFMA16(wAh[2][0], h0f0, bHN);
    aHN = MFMA16(wAh[2][1], h0f1, aHN);
    f32x4 my = aXN + rg * aHN;         // = -2log2e * (xn + r*hn)
    f32x4 ng = tanh4(my);
    hs = zg * (hs - ng) + ng;
    *(f16x4*)&H0w[widx] = pack4(hs[0], hs[1], hs[2], hs[3]);
  };

  // layer-1 step: read h0 from H0r, own state from H1r, write H1w
  auto stepB = [&](const f16* H0r, const f16* H1r, f16* H1w) {
    const f16x8 g0 = *(const f16x8*)&H0r[lane * 8];
    const f16x8 g1 = *(const f16x8*)&H0r[512 + lane * 8];
    const f16x8 h1f0 = *(const f16x8*)&H1r[lane * 8];
    const f16x8 h1f1 = *(const f16x8*)&H1r[512 + lane * 8];
    __builtin_amdgcn_s_setprio(1);
    f32x4 aR = MFMA16(wBx[0][0], g0, bR);
    f32x4 aZ = MFMA16(wBx[1][0], g0, bZ);
    aR = MFMA16(wBx[0][1], g1, aR);
    aZ = MFMA16(wBx[1][1], g1, aZ);
    aR = MFMA16(wBh[0][0], h1f0, aR);
    aZ = MFMA16(wBh[1][0], h1f0, aZ);
    aR = MFMA16(wBh[0][1], h1f1, aR);
    aZ = MFMA16(wBh[1][1], h1f1, aZ);
    __builtin_amdgcn_s_setprio(0);
    f32x4 rg, zg;
    sigmoid4(aR, aZ, rg, zg);          // trans burst...
    f32x4 aXN = MFMA16(wBx[2][0], g0, bXN);         // ...overlaps these MFMAs
    aXN = MFMA16(wBx[2][1], g1, aXN);
    f32x4 aHN = MFMA16(wBh[2][0], h1f0, bHN);
    aHN = MFMA16(wBh[2][1], h1f1, aHN);
    f32x4 my = aXN + rg * aHN;
    f32x4 ng = tanh4(my);
    hs = zg * (hs - ng) + ng;
    *(f16x4*)&H1w[widx] = pack4(hs[0], hs[1], hs[2], hs[3]);
  };

  __syncthreads();

  // x B-frag source (group A only): lane (l15,q) reads x[b0+l15][t][q*8..].
  // 2-deep prefetch in STATICALLY NAMED registers (slot0 = even t, slot1 = odd).
  const float* xbase = x + (size_t)(b0 + l15) * 4096 + q * 8;
  float4 xa0, xb0, xa1, xb1;
  if (!isB) {
    xa0 = *(const float4*)xbase;
    xb0 = *(const float4*)(xbase + 4);
    xa1 = *(const float4*)(xbase + 32);
    xb1 = *(const float4*)(xbase + 36);
  }

  for (int t = 0; t < 128; t += 2) {
    // ---- pipeline iteration t (parity 0): A step t, B step t-1
    if (!isB) {
      const float4 cxa = xa0, cxb = xb0;
      if (t + 2 < 128) {
        const float* xp = xbase + (t + 2) * 32;
        xa0 = *(const float4*)xp;
        xb0 = *(const float4*)(xp + 4);
      }
      stepA(H0[0], H0[1], cxa, cxb);
    } else if (t > 0) {
      stepB(H0[0], H1[0], H1[1]);
    }
    LDS_BARRIER();

    // ---- pipeline iteration t+1 (parity 1): A step t+1, B step t
    if (!isB) {
      const float4 cxa = xa1, cxb = xb1;
      if (t + 3 < 128) {
        const float* xp = xbase + (t + 3) * 32;
        xa1 = *(const float4*)xp;
        xb1 = *(const float4*)(xp + 4);
      }
      stepA(H0[1], H0[0], cxa, cxb);
    } else {
      stepB(H0[1], H1[1], H1[0]);
    }
    LDS_BARRIER();
  }
  // ---- pipeline iteration t=128 (parity 0): B step 127 only
  if (isB) stepB(H0[0], H1[0], H1[1]);

  // ---- fc: out[b] = sum_i h1[i]*fcw[i] + fcb   (group B holds h1(127))
  if (isB) {
    float partial = fw[0] * hs[0] + fw[1] * hs[1] + fw[2] * hs[2] + fw[3] * hs[3];
    partial += __shfl_down(partial, 16, 64);
    partial += __shfl_down(partial, 32, 64);
    if (lane < 16) red[wa][l15] = partial;
  }
  __syncthreads();
  if (tid < 16) out[b0 + tid] = red[0][tid] + red[1][tid] + red[2][tid] + red[3][tid] + fcb0;
}

extern "C" void kernel_launch(void* const* d_in, const int* in_sizes, int n_in,
                              void* d_out, int out_size, void* d_ws, size_t ws_size,
                              hipStream_t stream) {
  (void)in_sizes; (void)n_in; (void)out_size; (void)d_ws; (void)ws_size;
  const float* x    = (const float*)d_in[0];
  const float* Wih0 = (const float*)d_in[1];
  const float* Whh0 = (const float*)d_in[2];
  const float* bih0 = (const float*)d_in[3];
  const float* bhh0 = (const float*)d_in[4];
  const float* Wih1 = (const float*)d_in[5];
  const float* Whh1 = (const float*)d_in[6];
  const float* bih1 = (const float*)d_in[7];
  const float* bhh1 = (const float*)d_in[8];
  const float* fcw  = (const float*)d_in[9];
  const float* fcb  = (const float*)d_in[10];
  float* out = (float*)d_out;

  gru_fused<<<256, 512, 0, stream>>>(x, Wih0, Whh0, bih0, bhh0,
                                     Wih1, Whh1, bih1, bhh1, fcw, fcb, out);
}

// Round 8
// 176.849 us; speedup vs baseline: 2.5642x; 1.0156x over previous
//
#include <hip/hip_runtime.h>

typedef _Float16 f16;
typedef f16 f16x8 __attribute__((ext_vector_type(8)));
typedef f16 f16x4 __attribute__((ext_vector_type(4)));
typedef __fp16 h16x2 __attribute__((ext_vector_type(2)));   // cvt_pkrtz native type
typedef float f32x4 __attribute__((ext_vector_type(4)));
typedef float f32x2 __attribute__((ext_vector_type(2)));

#define MFMA16(A, B, C) __builtin_amdgcn_mfma_f32_16x16x32_f16((A), (B), (C), 0, 0, 0)

// Barrier WITHOUT vmcnt drain: only LDS (lgkmcnt) must be visible across it.
#define LDS_BARRIER() asm volatile("s_waitcnt lgkmcnt(0)\n\ts_barrier" ::: "memory")

__device__ __forceinline__ float E2(float x) {   // 2^x
#if __has_builtin(__builtin_amdgcn_exp2f)
  return __builtin_amdgcn_exp2f(x);
#else
  return __expf(x * 0.69314718056f);
#endif
}
__device__ __forceinline__ float RCP(float x) { return __builtin_amdgcn_rcpf(x); }

__device__ __forceinline__ f16x8 cvt8(float4 a, float4 b) {
  union { h16x2 h[4]; f16x8 v; } u;
  u.h[0] = __builtin_amdgcn_cvt_pkrtz(a.x, a.y);
  u.h[1] = __builtin_amdgcn_cvt_pkrtz(a.z, a.w);
  u.h[2] = __builtin_amdgcn_cvt_pkrtz(b.x, b.y);
  u.h[3] = __builtin_amdgcn_cvt_pkrtz(b.z, b.w);
  return u.v;
}

// scaled weight-load convert (init-time only)
__device__ __forceinline__ f16x8 cvt8s(const float* p, float s) {
  float4 a = *(const float4*)p;
  float4 b = *(const float4*)(p + 4);
  union { h16x2 h[4]; f16x8 v; } u;
  u.h[0] = __builtin_amdgcn_cvt_pkrtz(a.x * s, a.y * s);
  u.h[1] = __builtin_amdgcn_cvt_pkrtz(a.z * s, a.w * s);
  u.h[2] = __builtin_amdgcn_cvt_pkrtz(b.x * s, b.y * s);
  u.h[3] = __builtin_amdgcn_cvt_pkrtz(b.z * s, b.w * s);
  return u.v;
}

__device__ __forceinline__ f16x4 pack4(float a0, float a1, float a2, float a3) {
  union { h16x2 h2[2]; f16x4 v; } u;
  u.h2[0] = __builtin_amdgcn_cvt_pkrtz(a0, a1);
  u.h2[1] = __builtin_amdgcn_cvt_pkrtz(a2, a3);
  return u.v;
}

// ---- R7 gate math (kept): 4 rows at once, cross-row shared rcp.
// Pre-scales folded into weights/biases (R1-verified):
//   aR,aZ pre-multiplied by -log2(e); aXN,aHN pre-multiplied by -2log2(e).
// sigmoid4: 8 E2 + 2 rcp; tanh4: 4 E2 + 2 rcp.  Verified absmax 0.0039.
__device__ __forceinline__ void sigmoid4(f32x4 aR, f32x4 aZ,
                                         f32x4& rg, f32x4& zg) {
  f32x4 ea, eb;
  ea[0] = E2(aR[0]); ea[1] = E2(aR[1]); ea[2] = E2(aR[2]); ea[3] = E2(aR[3]);
  eb[0] = E2(aZ[0]); eb[1] = E2(aZ[1]); eb[2] = E2(aZ[2]); eb[3] = E2(aZ[3]);
  f32x4 pa = ea + 1.0f;
  f32x4 pb = eb + 1.0f;
  f32x4 prod = pa * pb;
  float i01 = RCP(prod[0] * prod[1]);
  float i23 = RCP(prod[2] * prod[3]);
  f32x4 invv;
  invv[0] = prod[1] * i01; invv[1] = prod[0] * i01;
  invv[2] = prod[3] * i23; invv[3] = prod[2] * i23;   // = 1/prod[i]
  rg = pb * invv;                  // sigmoid(r pre-act)
  zg = pa * invv;                  // sigmoid(z pre-act)
}
__device__ __forceinline__ f32x4 tanh4(f32x4 my) {     // my = -2log2e * y
  f32x4 c;
  c[0] = E2(my[0]); c[1] = E2(my[1]); c[2] = E2(my[2]); c[3] = E2(my[3]);
  f32x4 num = 1.0f - c;
  f32x4 den = 1.0f + c;
  float j01 = RCP(den[0] * den[1]);
  float j23 = RCP(den[2] * den[3]);
  f32x4 dv;
  dv[0] = den[1] * j01; dv[1] = den[0] * j01;
  dv[2] = den[3] * j23; dv[3] = den[2] * j23;          // = 1/den[i]
  return num * dv;                 // tanh(y)
}

// B=4096, T=128, D=32, H=64.  16 batch / WG, 8 waves (proven structure).
//
// R8: MFMA CHAIN REASSOCIATION.  R6/R7 established the interval is
// latency-chain-bound, not issue-bound (issue cuts of 10% -> 1.5%; +50%
// issue -> only +27% interval).  The remaining attackable chain segment is
// the accumulate depth feeding sigmoid: stepB's aR/aZ were 4-deep
// dependent MFMA chains (~64-96cy), stepA's 3-deep.  Split into two
// independent 2-deep chains + one packed f32 add: R/Z head-chain depth
// halves.  XN/HN chains feed the later tanh (slack) and stay chained.
// ds_reads ordered first-needed-first (g0, h1f0, g1, h1f1).
// Keeps: R7 shared-rcp gates, MFMA-after-sigmoid overlap, setprio,
// weight pre-scale fold.
//
// Waves 0-3 (group A): layer 0, step t.   Waves 4-7 (group B): layer 1, t-1.
// Time loop unrolled x2 (parity/prefetch compile-time).  One LDS-only
// s_barrier per pipeline step.
// H LDS layout: h[k] for batch b at f16 offset ((k>>3)*16+b)*8 + (k&7)
//   -> B-frag for lane L, kfrag f = stride-1 ds_read_b128 at f*1024 + L*16.
__launch_bounds__(512, 2)
__global__ void gru_fused(const float* __restrict__ x,
                          const float* __restrict__ Wih0, const float* __restrict__ Whh0,
                          const float* __restrict__ bih0, const float* __restrict__ bhh0,
                          const float* __restrict__ Wih1, const float* __restrict__ Whh1,
                          const float* __restrict__ bih1, const float* __restrict__ bhh1,
                          const float* __restrict__ fcw, const float* __restrict__ fcb,
                          float* __restrict__ out) {
  __shared__ f16 H0[2][1024];
  __shared__ f16 H1[2][1024];
  __shared__ float red[4][16];

  const int tid = threadIdx.x;
  const int wave = tid >> 6;
  const int lane = tid & 63;
  const int l15 = lane & 15;
  const int q = lane >> 4;
  const int wa = wave & 3;
  const bool isB = wave >= 4;
  const int b0 = blockIdx.x * 16;

  for (int i = tid; i < 2048; i += 512) {
    ((f16*)H0)[i] = (f16)0.0f;
    ((f16*)H1)[i] = (f16)0.0f;
  }

  const float SRZ = -1.44269504f;     // -log2(e)      folded into r,z rows
  const float SN  = -2.88539008f;     // -2*log2(e)    folded into n rows

  // ---- register-resident weight A-fragments: A[m=l15][k = kf*32 + q*8 + j]
  f16x8 wAx[3];          // layer0 Wih (K=32)       — group A only
  f16x8 wAh[3][2];       // layer0 Whh (K=64)       — group A only
  f16x8 wBx[3][2];       // layer1 Wih (K=64)       — group B only
  f16x8 wBh[3][2];       // layer1 Whh (K=64)       — group B only
  f32x4 bR, bZ, bXN, bHN;
  float fw[4] = {0.f, 0.f, 0.f, 0.f};

  if (!isB) {
#pragma unroll
    for (int g = 0; g < 3; ++g) {
      const float s = (g == 2) ? SN : SRZ;
      const int row = g * 64 + 16 * wa + l15;
      wAx[g] = cvt8s(Wih0 + row * 32 + q * 8, s);
#pragma unroll
      for (int kf = 0; kf < 2; ++kf) {
        wAh[g][kf] = cvt8s(Whh0 + row * 64 + kf * 32 + q * 8, s);
      }
    }
#pragma unroll
    for (int r = 0; r < 4; ++r) {
      const int o = 16 * wa + 4 * q + r;
      bR[r]  = SRZ * (bih0[o] + bhh0[o]);
      bZ[r]  = SRZ * (bih0[64 + o] + bhh0[64 + o]);
      bXN[r] = SN * bih0[128 + o];
      bHN[r] = SN * bhh0[128 + o];
    }
  } else {
#pragma unroll
    for (int g = 0; g < 3; ++g) {
      const float s = (g == 2) ? SN : SRZ;
      const int row = g * 64 + 16 * wa + l15;
#pragma unroll
      for (int kf = 0; kf < 2; ++kf) {
        wBx[g][kf] = cvt8s(Wih1 + row * 64 + kf * 32 + q * 8, s);
        wBh[g][kf] = cvt8s(Whh1 + row * 64 + kf * 32 + q * 8, s);
      }
    }
#pragma unroll
    for (int r = 0; r < 4; ++r) {
      const int o = 16 * wa + 4 * q + r;
      bR[r]  = SRZ * (bih1[o] + bhh1[o]);
      bZ[r]  = SRZ * (bih1[64 + o] + bhh1[64 + o]);
      bXN[r] = SN * bih1[128 + o];
      bHN[r] = SN * bhh1[128 + o];
      fw[r] = fcw[o];
    }
  }
  const float fcb0 = fcb[0];

  f32x4 hs = {0.f, 0.f, 0.f, 0.f};   // this lane's 4 h rows (own layer)

  const int wk0 = 16 * wa + 4 * q;                          // lane's 4 h-row base
  const int widx = ((wk0 >> 3) * 16 + l15) * 8 + (wk0 & 7); // f16 offset of b64 store

  const f32x4 ZERO = {0.f, 0.f, 0.f, 0.f};

  // layer-0 step: read H0r, consume x frag, write H0w.
  // R/Z: two independent chains (x-chain seeded bias, 2-deep; h-tail 1-deep)
  // + packed add.  Sigmoid burst overlaps the XN/HN MFMAs.
  auto stepA = [&](const f16* H0r, f16* H0w, float4 xav, float4 xbv) {
    const f16x8 h0f0 = *(const f16x8*)&H0r[lane * 8];
    const f16x8 h0f1 = *(const f16x8*)&H0r[512 + lane * 8];
    const f16x8 xf = cvt8(xav, xbv);
    __builtin_amdgcn_s_setprio(1);
    f32x4 cR1 = MFMA16(wAx[0], xf, bR);          // chain 1: bias + x
    f32x4 cZ1 = MFMA16(wAx[1], xf, bZ);
    cR1 = MFMA16(wAh[0][0], h0f0, cR1);          // chain 1: + h-frag0 (2-deep)
    cZ1 = MFMA16(wAh[1][0], h0f0, cZ1);
    f32x4 cR2 = MFMA16(wAh[0][1], h0f1, ZERO);   // chain 2: h-frag1 (1-deep)
    f32x4 cZ2 = MFMA16(wAh[1][1], h0f1, ZERO);
    __builtin_amdgcn_s_setprio(0);
    f32x4 aR = cR1 + cR2;
    f32x4 aZ = cZ1 + cZ2;
    f32x4 rg, zg;
    sigmoid4(aR, aZ, rg, zg);          // trans burst...
    f32x4 aXN = MFMA16(wAx[2], xf, bXN);            // ...overlaps these MFMAs
    f32x4 aHN = MFMA16(wAh[2][0], h0f0, bHN);
    aHN = MFMA16(wAh[2][1], h0f1, aHN);
    f32x4 my = aXN + rg * aHN;         // = -2log2e * (xn + r*hn)
    f32x4 ng = tanh4(my);
    hs = zg * (hs - ng) + ng;
    *(f16x4*)&H0w[widx] = pack4(hs[0], hs[1], hs[2], hs[3]);
  };

  // layer-1 step: read h0 from H0r, own state from H1r, write H1w.
  // R/Z: 4-deep chains split into 2∥2 + packed add.
  auto stepB = [&](const f16* H0r, const f16* H1r, f16* H1w) {
    const f16x8 g0   = *(const f16x8*)&H0r[lane * 8];
    const f16x8 h1f0 = *(const f16x8*)&H1r[lane * 8];
    const f16x8 g1   = *(const f16x8*)&H0r[512 + lane * 8];
    const f16x8 h1f1 = *(const f16x8*)&H1r[512 + lane * 8];
    __builtin_amdgcn_s_setprio(1);
    f32x4 cR1 = MFMA16(wBx[0][0], g0, bR);       // chain 1: bias + x-part
    f32x4 cZ1 = MFMA16(wBx[1][0], g0, bZ);
    f32x4 cR2 = MFMA16(wBh[0][0], h1f0, ZERO);   // chain 2: h-part
    f32x4 cZ2 = MFMA16(wBh[1][0], h1f0, ZERO);
    cR1 = MFMA16(wBx[0][1], g1, cR1);
    cZ1 = MFMA16(wBx[1][1], g1, cZ1);
    cR2 = MFMA16(wBh[0][1], h1f1, cR2);
    cZ2 = MFMA16(wBh[1][1], h1f1, cZ2);
    __builtin_amdgcn_s_setprio(0);
    f32x4 aR = cR1 + cR2;
    f32x4 aZ = cZ1 + cZ2;
    f32x4 rg, zg;
    sigmoid4(aR, aZ, rg, zg);          // trans burst...
    f32x4 aXN = MFMA16(wBx[2][0], g0, bXN);         // ...overlaps these MFMAs
    aXN = MFMA16(wBx[2][1], g1, aXN);
    f32x4 aHN = MFMA16(wBh[2][0], h1f0, bHN);
    aHN = MFMA16(wBh[2][1], h1f1, aHN);
    f32x4 my = aXN + rg * aHN;
    f32x4 ng = tanh4(my);
    hs = zg * (hs - ng) + ng;
    *(f16x4*)&H1w[widx] = pack4(hs[0], hs[1], hs[2], hs[3]);
  };

  __syncthreads();

  // x B-frag source (group A only): lane (l15,q) reads x[b0+l15][t][q*8..].
  // 2-deep prefetch in STATICALLY NAMED registers (slot0 = even t, slot1 = odd).
  const float* xbase = x + (size_t)(b0 + l15) * 4096 + q * 8;
  float4 xa0, xb0, xa1, xb1;
  if (!isB) {
    xa0 = *(const float4*)xbase;
    xb0 = *(const float4*)(xbase + 4);
    xa1 = *(const float4*)(xbase + 32);
    xb1 = *(const float4*)(xbase + 36);
  }

  for (int t = 0; t < 128; t += 2) {
    // ---- pipeline iteration t (parity 0): A step t, B step t-1
    if (!isB) {
      const float4 cxa = xa0, cxb = xb0;
      if (t + 2 < 128) {
        const float* xp = xbase + (t + 2) * 32;
        xa0 = *(const float4*)xp;
        xb0 = *(const float4*)(xp + 4);
      }
      stepA(H0[0], H0[1], cxa, cxb);
    } else if (t > 0) {
      stepB(H0[0], H1[0], H1[1]);
    }
    LDS_BARRIER();

    // ---- pipeline iteration t+1 (parity 1): A step t+1, B step t
    if (!isB) {
      const float4 cxa = xa1, cxb = xb1;
      if (t + 3 < 128) {
        const float* xp = xbase + (t + 3) * 32;
        xa1 = *(const float4*)xp;
        xb1 = *(const float4*)(xp + 4);
      }
      stepA(H0[1], H0[0], cxa, cxb);
    } else {
      stepB(H0[1], H1[1], H1[0]);
    }
    LDS_BARRIER();
  }
  // ---- pipeline iteration t=128 (parity 0): B step 127 only
  if (isB) stepB(H0[0], H1[0], H1[1]);

  // ---- fc: out[b] = sum_i h1[i]*fcw[i] + fcb   (group B holds h1(127))
  if (isB) {
    float partial = fw[0] * hs[0] + fw[1] * hs[1] + fw[2] * hs[2] + fw[3] * hs[3];
    partial += __shfl_down(partial, 16, 64);
    partial += __shfl_down(partial, 32, 64);
    if (lane < 16) red[wa][l15] = partial;
  }
  __syncthreads();
  if (tid < 16) out[b0 + tid] = red[0][tid] + red[1][tid] + red[2][tid] + red[3][tid] + fcb0;
}

extern "C" void kernel_launch(void* const* d_in, const int* in_sizes, int n_in,
                              void* d_out, int out_size, void* d_ws, size_t ws_size,
                              hipStream_t stream) {
  (void)in_sizes; (void)n_in; (void)out_size; (void)d_ws; (void)ws_size;
  const float* x    = (const float*)d_in[0];
  const float* Wih0 = (const float*)d_in[1];
  const float* Whh0 = (const float*)d_in[2];
  const float* bih0 = (const float*)d_in[3];
  const float* bhh0 = (const float*)d_in[4];
  const float* Wih1 = (const float*)d_in[5];
  const float* Whh1 = (const float*)d_in[6];
  const float* bih1 = (const float*)d_in[7];
  const float* bhh1 = (const float*)d_in[8];
  const float* fcw  = (const float*)d_in[9];
  const float* fcb  = (const float*)d_in[10];
  float* out = (float*)d_out;

  gru_fused<<<256, 512, 0, stream>>>(x, Wih0, Whh0, bih0, bhh0,
                                     Wih1, Whh1, bih1, bhh1, fcw, fcb, out);
}